// Round 2
// baseline (549.428 us; speedup 1.0000x reference)
//
#include <hip/hip_runtime.h>

using bf8 = __attribute__((ext_vector_type(8))) short;   // 8 bf16 (4 VGPRs) — MFMA A/B frag
using bf4 = __attribute__((ext_vector_type(4))) short;
using f4  = __attribute__((ext_vector_type(4))) float;   // MFMA C/D frag
using u16 = unsigned short;

#define NROWS 262144

// workspace byte layout (all 128B-aligned)
#define FLAG_B   0                       // int: 0 = bf16 inputs, 1 = fp32 inputs
#define PU_B     128                     // packed [U1;U2] frags: 32768 u16
#define PW2_B    (PU_B + 65536)          // packed [Whrz|Whn] frags: 49152 u16
#define PWI_B    (PW2_B + 98304)        // Wi^T as f32: [c(384)][k(4)]
#define BI_B     (PWI_B + 6144)          // bi as f32: 384
#define BHN_B    (BI_B + 1536)           // bhn as f32: 128
// total ~172 KB

#define PACK_ITEMS 83968                 // 32768 + 49152 + 1536 + 384 + 128

static __device__ __forceinline__ float bf2f(u16 u) {
    unsigned v = ((unsigned)u) << 16;
    return __builtin_bit_cast(float, v);
}
static __device__ __forceinline__ u16 f2bf(float f) {
    unsigned x = __builtin_bit_cast(unsigned, f);
    x = x + 0x7fffu + ((x >> 16) & 1u);          // RNE (inputs are finite)
    return (u16)(x >> 16);
}

// ---- dtype-dispatch helpers: FP32 => buffers hold float, else bf16 ----
template<bool FP32>
static __device__ __forceinline__ u16 ldw(const void* p, int i) {   // -> bf16 bits
    if constexpr (FP32) return f2bf(((const float*)p)[i]);
    else                return ((const u16*)p)[i];
}
template<bool FP32>
static __device__ __forceinline__ float ldf(const void* p, int i) { // -> float
    if constexpr (FP32) return ((const float*)p)[i];
    else                return bf2f(((const u16*)p)[i]);
}
template<bool FP32>
static __device__ __forceinline__ bf8 ld8(const void* base, int idx) { // 8 contiguous
    if constexpr (!FP32) {
        return *(const bf8*)((const u16*)base + idx);
    } else {
        const float* f = (const float*)base + idx;
        f4 u = *(const f4*)f;
        f4 v = *(const f4*)(f + 4);
        bf8 r;
        r[0]=(short)f2bf(u[0]); r[1]=(short)f2bf(u[1]); r[2]=(short)f2bf(u[2]); r[3]=(short)f2bf(u[3]);
        r[4]=(short)f2bf(v[0]); r[5]=(short)f2bf(v[1]); r[6]=(short)f2bf(v[2]); r[7]=(short)f2bf(v[3]);
        return r;
    }
}
template<bool FP32>
static __device__ __forceinline__ void st8(void* base, int idx, bf8 v) {
    if constexpr (!FP32) {
        *(bf8*)((u16*)base + idx) = v;
    } else {
        float* f = (float*)base + idx;
        f4 a, b;
        a[0]=bf2f((u16)v[0]); a[1]=bf2f((u16)v[1]); a[2]=bf2f((u16)v[2]); a[3]=bf2f((u16)v[3]);
        b[0]=bf2f((u16)v[4]); b[1]=bf2f((u16)v[5]); b[2]=bf2f((u16)v[6]); b[3]=bf2f((u16)v[7]);
        *(f4*)f = a; *(f4*)(f + 4) = b;
    }
}

// ---- mode detection: even-index u16s of real bf16 N(0,1) data never have
// exponent >= 0xC0 (|v| >= 2^65); fp32 data read as bf16 hits it ~25%/sample.
__global__ void detect_mode(const u16* __restrict__ h1u, int* __restrict__ flag) {
    if (threadIdx.x == 0 && blockIdx.x == 0) {
        int huge = 0;
#pragma unroll 8
        for (int i = 0; i < 256; ++i) {
            u16 v = h1u[i * 2];
            huge += (((v >> 7) & 0xFF) >= 0xC0);
        }
        *flag = (huge > 0) ? 1 : 0;
    }
}

// ---- pack weights into B-fragment order for mfma_f32_16x16x32_bf16:
// frag (nt,kb): lane l holds W[k = kb*32 + (l>>4)*8 + j][n = nt*16 + (l&15)], j=0..7
template<bool FP32>
__global__ void prep_pack(const void* __restrict__ U1, const void* __restrict__ U2,
                          const void* __restrict__ Whrz, const void* __restrict__ Whn,
                          const void* __restrict__ Wi, const void* __restrict__ bi,
                          const void* __restrict__ bhn, char* __restrict__ ws,
                          const int* __restrict__ flag)
{
    if ((*flag != 0) != FP32) return;
    int e = blockIdx.x * 256 + threadIdx.x;
    if (e >= PACK_ITEMS) return;
    u16*   pU   = (u16*)(ws + PU_B);
    u16*   pW2  = (u16*)(ws + PW2_B);
    float* wiF  = (float*)(ws + PWI_B);
    float* biF  = (float*)(ws + BI_B);
    float* bhnF = (float*)(ws + BHN_B);
    if (e < 32768) {                         // [U1;U2]: K=256 (KB=8), N=128 (NT=8)
        int j = e & 7, lane = (e >> 3) & 63, f = e >> 9;
        int kb = f & 7, nt = f >> 3;
        int k = kb * 32 + (lane >> 4) * 8 + j;
        int n = nt * 16 + (lane & 15);
        pU[e] = (k < 128) ? ldw<FP32>(U1, k * 128 + n) : ldw<FP32>(U2, (k - 128) * 128 + n);
    } else if (e < 81920) {                  // [Whrz|Whn]: K=128 (KB=4), N=384 (NT=24)
        int e2 = e - 32768;
        int j = e2 & 7, lane = (e2 >> 3) & 63, f = e2 >> 9;
        int kb = f & 3, nt = f >> 2;
        int k = kb * 32 + (lane >> 4) * 8 + j;
        int n = nt * 16 + (lane & 15);
        pW2[e2] = (n < 256) ? ldw<FP32>(Whrz, k * 256 + n) : ldw<FP32>(Whn, k * 128 + (n - 256));
    } else if (e < 83456) {                  // Wi^T [c][k] as f32
        int e3 = e - 81920;
        int k = e3 & 3, c = e3 >> 2;
        wiF[e3] = ldf<FP32>(Wi, k * 384 + c);
    } else if (e < 83840) {
        int i = e - 83456;  biF[i] = ldf<FP32>(bi, i);
    } else {
        int i = e - 83840;  bhnF[i] = ldf<FP32>(bhn, i);
    }
}

// ---- fused kernel: each wave independently owns 32 rows (two 16-row M-tiles
// sharing every B-frag). All LDS traffic is wave-private -> no __syncthreads.
template<bool FP32>
__global__ __launch_bounds__(256, 3) void gru_fused(
    const void* __restrict__ xin, const void* __restrict__ h1,
    const void* __restrict__ h2, const char* __restrict__ ws,
    void* __restrict__ out, const int* __restrict__ flag, int write2)
{
    if ((*flag != 0) != FP32) return;
    // stride 136 el = 272 B rows: 16B-aligned for ds b128, breaks pow2 banks
    __shared__ __align__(16) u16 hl[4][32][136];
    const int tid = threadIdx.x;
    const int w  = tid >> 6;
    const int l  = tid & 63;
    const int q  = l >> 4;        // quad index
    const int lr = l & 15;        // A-frag row / C-frag col
    const int g0 = blockIdx.x * 128 + w * 32;

    const bf8* __restrict__ pU  = (const bf8*)(ws + PU_B);
    const bf8* __restrict__ pW2 = (const bf8*)(ws + PW2_B);

    // ---------------- Phase A: h = [h1|h2] @ [U1;U2] ----------------
    // A-frag: lane holds A[row = lr][k = kb*32 + q*8 + j], contiguous in memory
    bf8 a[2][8];
#pragma unroll
    for (int m = 0; m < 2; ++m) {
        int row = g0 + m * 16 + lr;
        int base = row * 128 + q * 8;
#pragma unroll
        for (int kb = 0; kb < 4; ++kb) {
            a[m][kb]     = ld8<FP32>(h1, base + kb * 32);   // k in [0,128)   -> U1 rows
            a[m][kb + 4] = ld8<FP32>(h2, base + kb * 32);   // k in [128,256) -> U2 rows
        }
    }
#pragma unroll 1
    for (int nt = 0; nt < 8; ++nt) {
        f4 acc0 = {0.f, 0.f, 0.f, 0.f};
        f4 acc1 = {0.f, 0.f, 0.f, 0.f};
#pragma unroll
        for (int kb = 0; kb < 8; ++kb) {
            bf8 b = pU[(nt * 8 + kb) * 64 + l];
            acc0 = __builtin_amdgcn_mfma_f32_16x16x32_bf16(a[0][kb], b, acc0, 0, 0, 0);
            acc1 = __builtin_amdgcn_mfma_f32_16x16x32_bf16(a[1][kb], b, acc1, 0, 0, 0);
        }
        // C/D layout: col = lane&15, row = q*4 + reg  [m89-verified]
        int col = nt * 16 + lr;
#pragma unroll
        for (int i = 0; i < 4; ++i) {
            hl[w][q * 4 + i][col]      = f2bf(acc0[i]);
            hl[w][16 + q * 4 + i][col] = f2bf(acc1[i]);
        }
    }

    // ---------------- LDS round trip: h as A-operand ----------------
    bf8 ah[2][4];
#pragma unroll
    for (int m = 0; m < 2; ++m)
#pragma unroll
        for (int kb = 0; kb < 4; ++kb)
            ah[m][kb] = *(const bf8*)&hl[w][m * 16 + lr][kb * 32 + q * 8];

    // x rows for the VALU i_proj (epilogue rows are C-layout: q*4+i)
    float xf[2][4][4];
#pragma unroll
    for (int m = 0; m < 2; ++m)
#pragma unroll
        for (int i = 0; i < 4; ++i) {
            int row = g0 + m * 16 + q * 4 + i;
            if constexpr (FP32) {
                f4 xv = *(const f4*)((const float*)xin + row * 4);
#pragma unroll
                for (int k = 0; k < 4; ++k) xf[m][i][k] = xv[k];
            } else {
                bf4 xv = *(const bf4*)((const u16*)xin + row * 4);
#pragma unroll
                for (int k = 0; k < 4; ++k) xf[m][i][k] = bf2f((u16)xv[k]);
            }
        }

    const float* wiF  = (const float*)(ws + PWI_B);
    const float* biF  = (const float*)(ws + BI_B);
    const float* bhnF = (const float*)(ws + BHN_B);

    // ---------------- Phase C + epilogue, per 16-col group ----------------
#pragma unroll 1
    for (int nt = 0; nt < 8; ++nt) {
        f4 aR[2], aZ[2], aN[2];
#pragma unroll
        for (int m = 0; m < 2; ++m) {
            aR[m] = {0.f,0.f,0.f,0.f}; aZ[m] = {0.f,0.f,0.f,0.f}; aN[m] = {0.f,0.f,0.f,0.f};
        }
#pragma unroll
        for (int kb = 0; kb < 4; ++kb) {
            bf8 bR = pW2[((nt     ) * 4 + kb) * 64 + l];   // Whrz cols [0,128)   (hr)
            bf8 bZ = pW2[((nt + 8 ) * 4 + kb) * 64 + l];   // Whrz cols [128,256) (hz)
            bf8 bN = pW2[((nt + 16) * 4 + kb) * 64 + l];   // Whn
#pragma unroll
            for (int m = 0; m < 2; ++m) {
                aR[m] = __builtin_amdgcn_mfma_f32_16x16x32_bf16(ah[m][kb], bR, aR[m], 0, 0, 0);
                aZ[m] = __builtin_amdgcn_mfma_f32_16x16x32_bf16(ah[m][kb], bZ, aZ[m], 0, 0, 0);
                aN[m] = __builtin_amdgcn_mfma_f32_16x16x32_bf16(ah[m][kb], bN, aN[m], 0, 0, 0);
            }
        }
        int c = nt * 16 + lr;
        f4 wr = *(const f4*)(wiF + c * 4);
        f4 wz = *(const f4*)(wiF + (128 + c) * 4);
        f4 wn = *(const f4*)(wiF + (256 + c) * 4);
        float bir = biF[c], biz = biF[128 + c], bin = biF[256 + c], bhc = bhnF[c];
#pragma unroll
        for (int m = 0; m < 2; ++m)
#pragma unroll
            for (int i = 0; i < 4; ++i) {
                int rl = m * 16 + q * 4 + i;
                float ir = bir, iz = biz, inn = bin;
#pragma unroll
                for (int k = 0; k < 4; ++k) {
                    ir  = fmaf(xf[m][i][k], wr[k], ir);
                    iz  = fmaf(xf[m][i][k], wz[k], iz);
                    inn = fmaf(xf[m][i][k], wn[k], inn);
                }
                float hv = bf2f(hl[w][rl][c]);
                float sr = ir + aR[m][i];
                sr = fminf(fmaxf(sr, -30.f), 30.f);
                float r = __fdividef(1.f, 1.f + __expf(-sr));
                float sz = iz + aZ[m][i];
                sz = fminf(fmaxf(sz, -30.f), 30.f);
                float z = __fdividef(1.f, 1.f + __expf(-sz));
                float t = inn + r * (aN[m][i] + bhc);
                t = fminf(fmaxf(t, -15.f), 15.f);         // tanh saturates; avoid exp overflow
                float e2t = __expf(2.f * t);
                float n = (e2t - 1.f) * __fdividef(1.f, e2t + 1.f);
                float o = (1.f - z) * n + z * hv;
                hl[w][rl][c] = f2bf(o);                   // overwrite h in place
            }
    }

    // ---------------- vectorized copy-out (both output copies) ----------------
#pragma unroll
    for (int ii = 0; ii < 8; ++ii) {
        int ch  = ii * 64 + l;        // 512 chunks of 8 el for this wave's 32x128 tile
        int row = ch >> 4;
        int c8  = (ch & 15) * 8;
        bf8 v = *(const bf8*)&hl[w][row][c8];
        int off = (g0 + row) * 128 + c8;
        st8<FP32>(out, off, v);
        if (write2) st8<FP32>(out, NROWS * 128 + off, v);
    }
}

extern "C" void kernel_launch(void* const* d_in, const int* in_sizes, int n_in,
                              void* d_out, int out_size, void* d_ws, size_t ws_size,
                              hipStream_t stream) {
    const void* x    = d_in[0];
    const void* h1   = d_in[1];
    const void* h2   = d_in[2];
    const void* U1   = d_in[3];
    const void* U2   = d_in[4];
    const void* Wi   = d_in[5];
    const void* bi   = d_in[6];
    const void* Whrz = d_in[7];
    const void* Whn  = d_in[8];
    const void* bhn  = d_in[9];
    char* ws   = (char*)d_ws;
    int* flag  = (int*)(ws + FLAG_B);
    int write2 = (out_size >= 2 * NROWS * 128) ? 1 : 0;

    detect_mode<<<1, 64, 0, stream>>>((const u16*)h1, flag);
    const int pblk = (PACK_ITEMS + 255) / 256;
    prep_pack<false><<<pblk, 256, 0, stream>>>(U1, U2, Whrz, Whn, Wi, bi, bhn, ws, flag);
    prep_pack<true ><<<pblk, 256, 0, stream>>>(U1, U2, Whrz, Whn, Wi, bi, bhn, ws, flag);
    gru_fused<false><<<NROWS / 128, 256, 0, stream>>>(x, h1, h2, ws, d_out, flag, write2);
    gru_fused<true ><<<NROWS / 128, 256, 0, stream>>>(x, h1, h2, ws, d_out, flag, write2);
}